// Round 6
// baseline (125.162 us; speedup 1.0000x reference)
//
#include <hip/hip_runtime.h>

// Cost volume: out[b,d,h,w] = (1/C) * sum_c L[b,c,h,w] * R[b,c,h,w-d], zero for w<d.
// B=8, C=128, H=96, W=320, D=48, fp32.
//
// Round 6: attack per-chunk latency exposure (r5 showed occupancy-doubling was a
// no-op; wall/chunk = 17.7K cyc vs ~10K of pipe work -> stall cadence).
//  - CC=16 (8 chunks): per-chunk compute ~1100+ cyc > ~900 cyc HBM latency, so the
//    reg-staged prefetch (issued at chunk top, vmcnt-waited after compute) is fully
//    covered. Barriers: 16 -> 8.
//  - NBUF=2 (47 KB LDS), one barrier per chunk, write-after-compute is race-free:
//    buffer (t+1)&1 was last read in chunk t-1, and the barrier at end of t-1
//    ordered those reads before chunk t begins.
//  - Keep r5's validated pieces: C-split-2 (640 thr), L direct-from-global,
//    zero-padded R rows, LDS-transpose epilogue combine.

constexpr int Cn = 128, Hn = 96, Wn = 320, Dn = 48;
constexpr int CC = 16;                // channels staged per chunk
constexpr int RW = Wn + 48;           // padded R row = 368 floats
constexpr int NCH = Cn / CC;          // 8 chunks
constexpr size_t planeHW = (size_t)Hn * Wn;   // 30720

__global__ __launch_bounds__(640)
void costvol_kernel(const float* __restrict__ L, const float* __restrict__ R,
                    float* __restrict__ out) {
  __shared__ float Rs[2][CC][RW];      // 47104 B

  const int bh = blockIdx.x;
  const int b = bh / Hn, h = bh % Hn;
  const int tid = threadIdx.x;
  const int g = (tid >= 320) ? 1 : 0;  // channel-half
  const int t5 = tid - g * 320;        // tile index 0..319

  // Zero the 48-float left pads of both buffers (written once).
  for (int i = tid; i < 2 * CC * 48; i += 640) {
    const int bu = i / (CC * 48), rem = i % (CC * 48);
    Rs[bu][rem / 48][rem % 48] = 0.f;
  }

  const int wg = t5 % 80, dg = t5 / 80;      // 80 w-groups x 4 d-groups
  const int w0 = wg * 4, d0 = dg * 12;
  const int p0 = w0 - d0 + 36;               // aligned (mod 4) window base in Rs
  const int ccb = g * 8;                     // this thread's 8-channel sub-range

  float acc[12][4];
#pragma unroll
  for (int k = 0; k < 12; ++k)
#pragma unroll
    for (int i = 0; i < 4; ++i) acc[k][i] = 0.f;

  const size_t baseBH = (size_t)b * Cn * planeHW + (size_t)h * Wn;
  const size_t cstep = (size_t)CC * planeHW;

  // R staging map: 16 rows x 320 floats per chunk = 640 thr x 2 float4.
  // f in {tid, tid+640} -> row = f/80 (0..15), col = (f%80)*4. Coalesced 16B/lane.
  const int srow0 = tid / 80, scol = (tid % 80) * 4;
  const int srow1 = srow0 + 8;
  const float* Rp0 = R + baseBH + (size_t)srow0 * planeHW + scol;
  const float* Rp1 = R + baseBH + (size_t)srow1 * planeHW + scol;

  // L direct-from-global base for this thread's channel sub-range.
  const float* Lg = L + baseBH + (size_t)ccb * planeHW + w0;

  // ---- prologue: stage chunk 0 into buffer 0 ----
  float4 n0 = *(const float4*)Rp0; Rp0 += cstep;
  float4 n1 = *(const float4*)Rp1; Rp1 += cstep;
  *(float4*)&Rs[0][srow0][48 + scol] = n0;
  *(float4*)&Rs[0][srow1][48 + scol] = n1;
  __syncthreads();

  for (int t = 0; t < NCH; ++t) {
    const bool more = (t + 1 < NCH);
    // Issue next chunk's loads FIRST; vmcnt-wait happens at the ds_write below,
    // ~1100 cycles of FMA later -> HBM latency fully covered.
    if (more) {
      n0 = *(const float4*)Rp0; Rp0 += cstep;
      n1 = *(const float4*)Rp1; Rp1 += cstep;
    }

    const float* bufb = &Rs[t & 1][0][0];
    const float* Lc = Lg + (size_t)t * cstep;
#pragma unroll
    for (int cc = 0; cc < 8; ++cc) {
      const float4 lv = *(const float4*)(Lc + (size_t)cc * planeHW);
      const float* rrow = bufb + (size_t)(ccb + cc) * RW;
      float q[16];
#pragma unroll
      for (int tt = 0; tt < 4; ++tt) {
        const float4 qq = *(const float4*)&rrow[p0 + 4 * tt];
        q[4 * tt + 0] = qq.x; q[4 * tt + 1] = qq.y;
        q[4 * tt + 2] = qq.z; q[4 * tt + 3] = qq.w;
      }
      const float lw[4] = {lv.x, lv.y, lv.z, lv.w};
      // d = d0+k, w = w0+i needs R[w-d] at Rs col w0+i-d0-k+48 = p0 + (i-k+12)
#pragma unroll
      for (int k = 0; k < 12; ++k)
#pragma unroll
        for (int i = 0; i < 4; ++i)
          acc[k][i] += lw[i] * q[i - k + 12];
    }

    if (more) {
      *(float4*)&Rs[(t + 1) & 1][srow0][48 + scol] = n0;
      *(float4*)&Rs[(t + 1) & 1][srow1][48 + scol] = n1;
      __syncthreads();   // one barrier per chunk
    }
  }

  // ---- combine the two channel halves and store ----
  __syncthreads();                       // all compute reads of Rs done
  float4* xbuf = (float4*)&Rs[0][0][0];  // reuse: 6*320*16 B = 30720 <= 47104
  const size_t obase = ((size_t)b * Dn + d0) * planeHW + (size_t)h * Wn + w0;

#pragma unroll
  for (int halfd = 0; halfd < 2; ++halfd) {
    if (g == 1) {
#pragma unroll
      for (int k2 = 0; k2 < 6; ++k2) {
        const int k = halfd * 6 + k2;
        float4 v;
        v.x = acc[k][0]; v.y = acc[k][1]; v.z = acc[k][2]; v.w = acc[k][3];
        xbuf[k2 * 320 + t5] = v;         // lane-contiguous: conflict-free
      }
    }
    __syncthreads();
    if (g == 0) {
#pragma unroll
      for (int k2 = 0; k2 < 6; ++k2) {
        const int k = halfd * 6 + k2;
        const float4 v = xbuf[k2 * 320 + t5];
        float4 o;
        o.x = (acc[k][0] + v.x) * (1.f / 128.f);
        o.y = (acc[k][1] + v.y) * (1.f / 128.f);
        o.z = (acc[k][2] + v.z) * (1.f / 128.f);
        o.w = (acc[k][3] + v.w) * (1.f / 128.f);
        *(float4*)(out + obase + (size_t)k * planeHW) = o;
      }
    }
    __syncthreads();
  }
}

extern "C" void kernel_launch(void* const* d_in, const int* in_sizes, int n_in,
                              void* d_out, int out_size, void* d_ws, size_t ws_size,
                              hipStream_t stream) {
  const float* Lf = (const float*)d_in[0];
  const float* Rf = (const float*)d_in[1];
  float* outp = (float*)d_out;
  const int B = 8;
  costvol_kernel<<<dim3(B * Hn), dim3(640), 0, stream>>>(Lf, Rf, outp);
}

// Round 7
// 93.480 us; speedup vs baseline: 1.3389x; 1.3389x over previous
//
#include <hip/hip_runtime.h>

// Cost volume: out[b,d,h,w] = (1/C) * sum_c L[b,c,h,w] * R[b,c,h,w-d], zero for w<d.
// B=8, C=128, H=96, W=320, D=48, fp32.
//
// Round 7: r5 was DS-pipe-bound (~87%: 3.93M wave ds_read_b128 x 12cyc + 61K conflict
// cyc/CU vs 283K wall). Halve the DS traffic: stage R in LDS as f16 CHANNEL-PAIRS
// (half2 = {c_even, c_odd}) and use v_dot2_f32_f16 (fp32 accumulate) so each
// ds_read_b128 feeds 2 channels and each VALU op does 2 MACs.
// Skeleton = r5 (verified): C-split-2 640 thr, L direct-from-global, NBUF=3
// reg-staged prefetch pipeline, zero-padded R rows, LDS-transpose epilogue.
// r6 lesson: CC=16 variant added 76MB of mystery scratch/thrash traffic — reverted.

typedef _Float16 h2 __attribute__((ext_vector_type(2)));

#if __has_builtin(__builtin_amdgcn_fdot2)
__device__ __forceinline__ float FDOT2(h2 a, h2 b, float c) {
  return __builtin_amdgcn_fdot2(a, b, c, false);
}
#else
__device__ __forceinline__ float FDOT2(h2 a, h2 b, float c) {
  c += (float)a.x * (float)b.x;
  c += (float)a.y * (float)b.y;
  return c;
}
#endif

__device__ __forceinline__ h2 uint_as_h2(unsigned u) {
  h2 r; __builtin_memcpy(&r, &u, 4); return r;
}
__device__ __forceinline__ unsigned pack2(float x, float y) {
  h2 v; v.x = (_Float16)x; v.y = (_Float16)y;
  unsigned u; __builtin_memcpy(&u, &v, 4); return u;
}

constexpr int Cn = 128, Hn = 96, Wn = 320, Dn = 48;
constexpr int CC = 8;                 // channels per chunk (4 f16-pairs)
constexpr int NPAIR = 4;              // pair-rows per chunk
constexpr int RWu = Wn + 48;          // padded row = 368 u32 (pair) elems
constexpr int NCH = Cn / CC;          // 16 chunks
constexpr int NBUF = 3;               // triple buffer
constexpr size_t planeHW = (size_t)Hn * Wn;   // 30720

// smem pool: Rs view needs NBUF*NPAIR*RWu = 4416 u32; epilogue xbuf needs 7680 u32.
constexpr int SMEM_U32 = 7680;

__device__ __forceinline__
void compute_chunk(const unsigned* __restrict__ rs,  // &Rs[buf][0][0]
                   int cpb, int p0,
                   const float* __restrict__ Lc,     // L at (chunk, ccb, h, w0)
                   float acc[12][4]) {
  const float4 l0 = *(const float4*)(Lc + 0 * planeHW);
  const float4 l1 = *(const float4*)(Lc + 1 * planeHW);
  const float4 l2 = *(const float4*)(Lc + 2 * planeHW);
  const float4 l3 = *(const float4*)(Lc + 3 * planeHW);
  const float a0[4] = {l0.x, l0.y, l0.z, l0.w};
  const float a1[4] = {l1.x, l1.y, l1.z, l1.w};
  const float a2[4] = {l2.x, l2.y, l2.z, l2.w};
  const float a3[4] = {l3.x, l3.y, l3.z, l3.w};
  h2 lpa[4], lpb[4];
#pragma unroll
  for (int i = 0; i < 4; ++i) {
    lpa[i] = uint_as_h2(pack2(a0[i], a1[i]));   // channels ccb, ccb+1
    lpb[i] = uint_as_h2(pack2(a2[i], a3[i]));   // channels ccb+2, ccb+3
  }

  // pair 0
  {
    const unsigned* prow = rs + (size_t)(cpb + 0) * RWu;
    unsigned q[16];
#pragma unroll
    for (int tt = 0; tt < 4; ++tt) {
      const uint4 qq = *(const uint4*)(prow + p0 + 4 * tt);
      q[4 * tt + 0] = qq.x; q[4 * tt + 1] = qq.y;
      q[4 * tt + 2] = qq.z; q[4 * tt + 3] = qq.w;
    }
#pragma unroll
    for (int k = 0; k < 12; ++k)
#pragma unroll
      for (int i = 0; i < 4; ++i)
        acc[k][i] = FDOT2(lpa[i], uint_as_h2(q[i - k + 12]), acc[k][i]);
  }
  // pair 1
  {
    const unsigned* prow = rs + (size_t)(cpb + 1) * RWu;
    unsigned q[16];
#pragma unroll
    for (int tt = 0; tt < 4; ++tt) {
      const uint4 qq = *(const uint4*)(prow + p0 + 4 * tt);
      q[4 * tt + 0] = qq.x; q[4 * tt + 1] = qq.y;
      q[4 * tt + 2] = qq.z; q[4 * tt + 3] = qq.w;
    }
#pragma unroll
    for (int k = 0; k < 12; ++k)
#pragma unroll
      for (int i = 0; i < 4; ++i)
        acc[k][i] = FDOT2(lpb[i], uint_as_h2(q[i - k + 12]), acc[k][i]);
  }
}

__global__ __launch_bounds__(640)
void costvol_kernel(const float* __restrict__ L, const float* __restrict__ R,
                    float* __restrict__ out) {
  __shared__ unsigned smem[SMEM_U32];
  auto Rs = reinterpret_cast<unsigned (*)[NPAIR][RWu]>(smem);  // [NBUF][4][368]

  const int bh = blockIdx.x;
  const int b = bh / Hn, h = bh % Hn;
  const int tid = threadIdx.x;
  const int g = (tid >= 320) ? 1 : 0;  // channel-half
  const int t5 = tid - g * 320;        // tile index 0..319

  // Zero the 48-elem left pads of all buffers (written once, never overwritten).
  for (int i = tid; i < NBUF * NPAIR * 48; i += 640) {
    const int bu = i / (NPAIR * 48), rem = i % (NPAIR * 48);
    Rs[bu][rem / 48][rem % 48] = 0u;
  }

  const int wg = t5 % 80, dg = t5 / 80;      // 80 w-groups x 4 d-groups
  const int w0 = wg * 4, d0 = dg * 12;
  const int p0 = w0 - d0 + 36;               // (mod 4)-aligned window base (u32 units)
  const int ccb = g * 4;                     // channel sub-range base
  const int cpb = g * 2;                     // pair-row base

  float acc[12][4];
#pragma unroll
  for (int k = 0; k < 12; ++k)
#pragma unroll
    for (int i = 0; i < 4; ++i) acc[k][i] = 0.f;

  const size_t baseBH = (size_t)b * Cn * planeHW + (size_t)h * Wn;
  const size_t cstep = (size_t)CC * planeHW;

  // R staging: threads 0..319 each stage one pair-row segment:
  // sq = tid/80 (pair 0..3 -> channels 2sq,2sq+1), scol = (tid%80)*4.
  const int sq = tid / 80, scol = (tid % 80) * 4;
  const float* Rp0 = R + baseBH + (size_t)(2 * sq) * planeHW + scol;
  const float* Rp1 = Rp0 + planeHW;

  // L direct-from-global base for this thread's channel sub-range.
  const float* Lg = L + baseBH + (size_t)ccb * planeHW + w0;

  float4 rAa, rAb, rBa, rBb;

  // ---- prologue: stage chunk 0 -> Rs[0]; load chunk 1 -> rA ----
  if (tid < 320) {
    rAa = *(const float4*)Rp0; rAb = *(const float4*)Rp1;
    Rp0 += cstep; Rp1 += cstep;
    uint4 u;
    u.x = pack2(rAa.x, rAb.x); u.y = pack2(rAa.y, rAb.y);
    u.z = pack2(rAa.z, rAb.z); u.w = pack2(rAa.w, rAb.w);
    *(uint4*)&Rs[0][sq][48 + scol] = u;
    rAa = *(const float4*)Rp0; rAb = *(const float4*)Rp1;
    Rp0 += cstep; Rp1 += cstep;
  }
  __syncthreads();

  for (int t = 0; t < NCH; t += 2) {
    // chunk t
    if (t + 1 < NCH) {
      if (tid < 320) {
        uint4 u;
        u.x = pack2(rAa.x, rAb.x); u.y = pack2(rAa.y, rAb.y);
        u.z = pack2(rAa.z, rAb.z); u.w = pack2(rAa.w, rAb.w);
        *(uint4*)&Rs[(t + 1) % 3][sq][48 + scol] = u;
      }
      __syncthreads();
    }
    if (t + 2 < NCH && tid < 320) {
      rBa = *(const float4*)Rp0; rBb = *(const float4*)Rp1;
      Rp0 += cstep; Rp1 += cstep;
    }
    compute_chunk(&Rs[t % 3][0][0], cpb, p0, Lg + (size_t)t * cstep, acc);
    // chunk t+1
    if (t + 1 < NCH) {
      if (t + 2 < NCH) {
        if (tid < 320) {
          uint4 u;
          u.x = pack2(rBa.x, rBb.x); u.y = pack2(rBa.y, rBb.y);
          u.z = pack2(rBa.z, rBb.z); u.w = pack2(rBa.w, rBb.w);
          *(uint4*)&Rs[(t + 2) % 3][sq][48 + scol] = u;
        }
        __syncthreads();
      }
      if (t + 3 < NCH && tid < 320) {
        rAa = *(const float4*)Rp0; rAb = *(const float4*)Rp1;
        Rp0 += cstep; Rp1 += cstep;
      }
      compute_chunk(&Rs[(t + 1) % 3][0][0], cpb, p0, Lg + (size_t)(t + 1) * cstep, acc);
    }
  }

  // ---- combine the two channel halves and store ----
  __syncthreads();                       // all compute reads of Rs done
  float4* xbuf = (float4*)smem;          // 1920 float4 = 30720 B <= SMEM
  const size_t obase = ((size_t)b * Dn + d0) * planeHW + (size_t)h * Wn + w0;

#pragma unroll
  for (int halfd = 0; halfd < 2; ++halfd) {
    if (g == 1) {
#pragma unroll
      for (int k2 = 0; k2 < 6; ++k2) {
        const int k = halfd * 6 + k2;
        float4 v;
        v.x = acc[k][0]; v.y = acc[k][1]; v.z = acc[k][2]; v.w = acc[k][3];
        xbuf[k2 * 320 + t5] = v;         // lane-contiguous: conflict-free
      }
    }
    __syncthreads();
    if (g == 0) {
#pragma unroll
      for (int k2 = 0; k2 < 6; ++k2) {
        const int k = halfd * 6 + k2;
        const float4 v = xbuf[k2 * 320 + t5];
        float4 o;
        o.x = (acc[k][0] + v.x) * (1.f / 128.f);
        o.y = (acc[k][1] + v.y) * (1.f / 128.f);
        o.z = (acc[k][2] + v.z) * (1.f / 128.f);
        o.w = (acc[k][3] + v.w) * (1.f / 128.f);
        *(float4*)(out + obase + (size_t)k * planeHW) = o;
      }
    }
    __syncthreads();
  }
}

extern "C" void kernel_launch(void* const* d_in, const int* in_sizes, int n_in,
                              void* d_out, int out_size, void* d_ws, size_t ws_size,
                              hipStream_t stream) {
  const float* Lf = (const float*)d_in[0];
  const float* Rf = (const float*)d_in[1];
  float* outp = (float*)d_out;
  const int B = 8;
  costvol_kernel<<<dim3(B * Hn), dim3(640), 0, stream>>>(Lf, Rf, outp);
}

// Round 8
// 67.464 us; speedup vs baseline: 1.8552x; 1.3856x over previous
//
#include <hip/hip_runtime.h>

// Cost volume: out[b,d,h,w] = (1/C) * sum_c L[b,c,h,w] * R[b,c,h,w-d], zero for w<d.
// B=8, C=128, H=96, W=320, D=48, fp32.
//
// Round 8: BARRIER-FREE wave-private pipeline.
// Evidence: r5 (occupancy x2), r7 (DS /2) both null; no pipe >65%. Theory: hipcc
// drains vmcnt(0) at every __syncthreads (guide m97), so the 16 barriers/loop
// serialize the R prefetch -> ~full loaded-HBM latency exposed per chunk, all
// waves phase-locked. Fix: each wave owns a 64w x 48d x C output tile and stages
// its R window into WAVE-PRIVATE LDS. No __syncthreads anywhere; intra-wave
// lgkmcnt ordering only; waves free-run and hide each other's stalls.
//
// Wave layout: lane = (dq<<4)|lq; lq: 16 w-groups x 4w, dq: 4 d-groups x 12d.
// R window per 8-ch chunk: 4 f16-pair rows x 128 cols [wbase-48, wbase+80).
// Boundary: stage addrs clamped to [0,316] (4-aligned -> each float4 fully-valid
// or fully-don't-care); invalid (w<d) outputs zeroed at store.

typedef _Float16 h2 __attribute__((ext_vector_type(2)));

#if __has_builtin(__builtin_amdgcn_fdot2)
__device__ __forceinline__ float FDOT2(unsigned a, unsigned b, float c) {
  h2 ha, hb; __builtin_memcpy(&ha, &a, 4); __builtin_memcpy(&hb, &b, 4);
  return __builtin_amdgcn_fdot2(ha, hb, c, false);
}
#else
__device__ __forceinline__ float FDOT2(unsigned a, unsigned b, float c) {
  h2 ha, hb; __builtin_memcpy(&ha, &a, 4); __builtin_memcpy(&hb, &b, 4);
  c += (float)ha.x * (float)hb.x;
  c += (float)ha.y * (float)hb.y;
  return c;
}
#endif

__device__ __forceinline__ unsigned pack2(float x, float y) {
  h2 v; v.x = (_Float16)x; v.y = (_Float16)y;
  unsigned u; __builtin_memcpy(&u, &v, 4); return u;
}

constexpr int Cn = 128, Hn = 96, Wn = 320, Dn = 48;
constexpr int NCH = 16;               // chunks of 8 channels (4 f16-pair rows)
constexpr int PRW = 128;              // u32 cols per pair-row window
constexpr size_t planeHW = (size_t)Hn * Wn;   // 30720

__global__ __launch_bounds__(256)
void costvol_kernel(const float* __restrict__ L, const float* __restrict__ R,
                    float* __restrict__ out) {
  __shared__ unsigned smem[4][2][4][PRW];   // [wave][buf][pair][128] = 16 KB

  const int tid = threadIdx.x;
  const int wid = tid >> 6, lane = tid & 63;
  const int gw = blockIdx.x * 4 + wid;       // 3840 waves = 768 (b,h) x 5 w-slots
  const int bh = gw / 5, ws = gw - bh * 5;
  const int b = bh / Hn, h = bh - b * Hn;
  const int wbase = ws * 64;

  const int lq = lane & 15, dq = lane >> 4;
  const int w0 = wbase + 4 * lq;             // this lane's 4 w's
  const int d0 = 12 * dq;                    // this lane's 12 d's
  const int j0 = 4 * lq - 12 * dq + 36;      // q window base in pair-row (0..96)

  // Stage mapping: lanes 0..31 -> pair sp=0, lanes 32..63 -> sp=1, col 4*sl.
  const int sl = lane & 31, sp = lane >> 5;
  int co = wbase + 4 * sl - 48;              // 4-aligned window column
  co = co < 0 ? 0 : (co > 316 ? 316 : co);   // clamp: garbage lands only in don't-care slots

  const size_t rowR = (size_t)b * Cn * planeHW + (size_t)h * Wn;
  const float* Re0 = R + rowR + (size_t)(2 * sp) * planeHW + co;       // pairs 0,1
  const float* Re1 = R + rowR + (size_t)(4 + 2 * sp) * planeHW + co;   // pairs 2,3
  const float* Lb  = L + rowR + w0;

  unsigned (*myb)[4][PRW] = smem[wid];       // wave-private

  float acc[12][4];
#pragma unroll
  for (int k = 0; k < 12; ++k)
#pragma unroll
    for (int i = 0; i < 4; ++i) acc[k][i] = 0.f;

  // ---- prologue: stage chunk 0 into buf 0 ----
  {
    const float4 e0 = *(const float4*)(Re0);
    const float4 o0 = *(const float4*)(Re0 + planeHW);
    const float4 e1 = *(const float4*)(Re1);
    const float4 o1 = *(const float4*)(Re1 + planeHW);
    uint4 u0, u1;
    u0.x = pack2(e0.x, o0.x); u0.y = pack2(e0.y, o0.y);
    u0.z = pack2(e0.z, o0.z); u0.w = pack2(e0.w, o0.w);
    u1.x = pack2(e1.x, o1.x); u1.y = pack2(e1.y, o1.y);
    u1.z = pack2(e1.z, o1.z); u1.w = pack2(e1.w, o1.w);
    *(uint4*)&myb[0][sp][4 * sl] = u0;
    *(uint4*)&myb[0][2 + sp][4 * sl] = u1;
  }

#pragma unroll 2
  for (int t = 0; t < NCH; ++t) {
    const int buf = t & 1;
    const float* Lc = Lb + (size_t)(8 * t) * planeHW;

    // L loads issued FIRST (so their consumption uses a counted vmcnt that
    // does not wait on the R prefetch issued below).
    float4 lv0 = *(const float4*)(Lc + 0 * planeHW);
    float4 lv1 = *(const float4*)(Lc + 1 * planeHW);
    float4 lv2 = *(const float4*)(Lc + 2 * planeHW);
    float4 lv3 = *(const float4*)(Lc + 3 * planeHW);
    float4 lv4 = *(const float4*)(Lc + 4 * planeHW);
    float4 lv5 = *(const float4*)(Lc + 5 * planeHW);
    float4 lv6 = *(const float4*)(Lc + 6 * planeHW);
    float4 lv7 = *(const float4*)(Lc + 7 * planeHW);

    // R prefetch for chunk t+1 (issue now, ds_write after compute).
    float4 e0, o0, e1, o1;
    if (t + 1 < NCH) {
      const size_t coff = (size_t)(8 * (t + 1)) * planeHW;
      e0 = *(const float4*)(Re0 + coff);
      o0 = *(const float4*)(Re0 + coff + planeHW);
      e1 = *(const float4*)(Re1 + coff);
      o1 = *(const float4*)(Re1 + coff + planeHW);
    }

    // ---- compute chunk t from wave-private buf ----
#pragma unroll
    for (int pr = 0; pr < 4; ++pr) {
      const float4 lE = (pr == 0) ? lv0 : (pr == 1) ? lv2 : (pr == 2) ? lv4 : lv6;
      const float4 lO = (pr == 0) ? lv1 : (pr == 1) ? lv3 : (pr == 2) ? lv5 : lv7;
      unsigned lp[4];
      lp[0] = pack2(lE.x, lO.x); lp[1] = pack2(lE.y, lO.y);
      lp[2] = pack2(lE.z, lO.z); lp[3] = pack2(lE.w, lO.w);
      const unsigned* prow = &myb[buf][pr][0];
      unsigned q[16];
#pragma unroll
      for (int tt = 0; tt < 4; ++tt) {
        const uint4 qq = *(const uint4*)(prow + j0 + 4 * tt);
        q[4 * tt + 0] = qq.x; q[4 * tt + 1] = qq.y;
        q[4 * tt + 2] = qq.z; q[4 * tt + 3] = qq.w;
      }
      // d=d0+k, w=w0+i -> R column w0+i-d0-k = pair-row index j0 + (i-k+12)
#pragma unroll
      for (int k = 0; k < 12; ++k)
#pragma unroll
        for (int i = 0; i < 4; ++i)
          acc[k][i] = FDOT2(lp[i], q[i - k + 12], acc[k][i]);
    }

    // ---- write prefetched chunk t+1 into the other private buffer ----
    if (t + 1 < NCH) {
      uint4 u0, u1;
      u0.x = pack2(e0.x, o0.x); u0.y = pack2(e0.y, o0.y);
      u0.z = pack2(e0.z, o0.z); u0.w = pack2(e0.w, o0.w);
      u1.x = pack2(e1.x, o1.x); u1.y = pack2(e1.y, o1.y);
      u1.z = pack2(e1.z, o1.z); u1.w = pack2(e1.w, o1.w);
      *(uint4*)&myb[buf ^ 1][sp][4 * sl] = u0;
      *(uint4*)&myb[buf ^ 1][2 + sp][4 * sl] = u1;
    }
  }

  // ---- store: zero the w<d positions, scale by 1/128 ----
  const float s = 1.f / 128.f;
#pragma unroll
  for (int k = 0; k < 12; ++k) {
    float4 o;
    o.x = (w0 + 0 >= d0 + k) ? acc[k][0] * s : 0.f;
    o.y = (w0 + 1 >= d0 + k) ? acc[k][1] * s : 0.f;
    o.z = (w0 + 2 >= d0 + k) ? acc[k][2] * s : 0.f;
    o.w = (w0 + 3 >= d0 + k) ? acc[k][3] * s : 0.f;
    *(float4*)(out + ((size_t)b * Dn + d0 + k) * planeHW + (size_t)h * Wn + w0) = o;
  }
}

extern "C" void kernel_launch(void* const* d_in, const int* in_sizes, int n_in,
                              void* d_out, int out_size, void* d_ws, size_t ws_size,
                              hipStream_t stream) {
  const float* Lf = (const float*)d_in[0];
  const float* Rf = (const float*)d_in[1];
  float* outp = (float*)d_out;
  // 3840 waves = 768 (b,h) x 5 w-slots; 4 waves per 256-thread block.
  costvol_kernel<<<dim3(960), dim3(256), 0, stream>>>(Lf, Rf, outp);
}